// Round 26
// baseline (307.671 us; speedup 1.0000x reference)
//
#include <hip/hip_runtime.h>

using f16 = _Float16;
typedef _Float16 h8 __attribute__((ext_vector_type(8)));
typedef _Float16 h4 __attribute__((ext_vector_type(4)));
typedef float f4 __attribute__((ext_vector_type(4)));
typedef unsigned int u32;
typedef unsigned long long u64;

#define DEVI static __device__ __forceinline__

DEVI f4 mfma16(h8 a, h8 b, f4 c) {
  return __builtin_amdgcn_mfma_f32_16x16x32_f16(a, b, c, 0, 0, 0);
}

// async global->LDS, 16B per lane. lds base must be wave-uniform; HW scatters lane i at base + i*16.
DEVI void gl_lds16(const f16* g, f16* l) {
  __builtin_amdgcn_global_load_lds(
      (const __attribute__((address_space(1))) u32*)g,
      (__attribute__((address_space(3))) u32*)l, 16, 0, 0);
}

DEVI u32 pkh2(float a, float b) {
  union { f16 h[2]; u32 u; } x;
  x.h[0] = (f16)a; x.h[1] = (f16)b;
  return x.u;
}

typedef float fv4 __attribute__((ext_vector_type(4)));

// ---------------- fused prep: fp32->fp16 converts (x, Wqkv, Wo) + RoPE table ----------------
__global__ __launch_bounds__(256) void k_prep(const float* __restrict__ x,
                                              const float* __restrict__ wqkv,
                                              const float* __restrict__ wo,
                                              f16* __restrict__ xb,
                                              f16* __restrict__ wqkvb,
                                              f16* __restrict__ wob,
                                              float* __restrict__ tbl) {
  int i = blockIdx.x * 256 + threadIdx.x;
  if (i < 6291456) {
    const float* src; f16* dst; int off;
    if (i < 2097152)      { src = x;    dst = xb;    off = i; }
    else if (i < 5242880) { src = wqkv; dst = wqkvb; off = i - 2097152; }
    else                  { src = wo;   dst = wob;   off = i - 5242880; }
    fv4 v = ((const fv4*)src)[off];
    h4 o;
    o[0] = (f16)v[0]; o[1] = (f16)v[1]; o[2] = (f16)v[2]; o[3] = (f16)v[3];
    ((h4*)dst)[off] = o;
  } else {
    int i2 = i - 6291456;  // < 131072
    int t = i2 >> 6, d = i2 & 63;
    float invf = exp2f(-(float)d * (13.287712379549449f / 64.f));
    float a = (float)t * invf;
    tbl[2 * i2]     = cosf(a);
    tbl[2 * i2 + 1] = sinf(a);
  }
}

// ---------------- QKV GEMM: m97 structure + fused RoPE epilogue (best-total, 7x verified) ----------------
__global__ __launch_bounds__(256) void k_gemm_qkv(const f16* __restrict__ A,
                                                  const f16* __restrict__ Bt,
                                                  const float* __restrict__ bias,
                                                  const float* __restrict__ tbl,
                                                  f16* __restrict__ Qb,
                                                  f16* __restrict__ Kb,
                                                  f16* __restrict__ qkvb,
                                                  int K) {
  __shared__ f16 sA[128 * 64];
  __shared__ f16 sB[128 * 64];
  const int tid = threadIdx.x;
  const int w = tid >> 6, lane = tid & 63;
  const int g = lane >> 4, colq = lane & 15;
  const int wr = w >> 1, wc = w & 1;

  const int nwg = gridDim.x;
  const int q8 = nwg >> 3;
  const int swz = (blockIdx.x & 7) * q8 + (blockIdx.x >> 3);
  const int bm = swz & 31, bn = swz >> 5;  // gy = 32

  const f16* Ab = A + (size_t)bm * 128 * K;
  const f16* Bb = Bt + (size_t)bn * 128 * K;
  const int nt = K >> 6;

  const int srow = lane >> 3;
  const int schunk = (lane & 7) ^ srow;
  const int cq7 = colq & 7;

  f4 acc[4][4] = {};
  const int rowA0 = wr * 64 + colq;
  const int rowB0 = wc * 64 + colq;

  for (int t = 0; t < nt; ++t) {
    const int k0 = t << 6;
#pragma unroll
    for (int j = 0; j < 4; ++j) {
      const int r = (w * 4 + j) * 8;
      gl_lds16(Ab + (size_t)(r + srow) * K + k0 + schunk * 8, sA + r * 64);
      gl_lds16(Bb + (size_t)(r + srow) * K + k0 + schunk * 8, sB + r * 64);
    }
    __syncthreads();
    h8 af[2][4], bf[2][4];
#pragma unroll
    for (int kki = 0; kki < 2; ++kki) {
#pragma unroll
      for (int m = 0; m < 4; ++m)
        af[kki][m] = *(const h8*)(sA + (rowA0 + m * 16) * 64 + (((kki * 4 + g) ^ cq7) * 8));
#pragma unroll
      for (int n = 0; n < 4; ++n)
        bf[kki][n] = *(const h8*)(sB + (rowB0 + n * 16) * 64 + (((kki * 4 + g) ^ cq7) * 8));
    }
#pragma unroll
    for (int m = 0; m < 4; ++m)
#pragma unroll
      for (int n = 0; n < 4; ++n)
#pragma unroll
        for (int kki = 0; kki < 2; ++kki)
          acc[m][n] = mfma16(af[kki][m], bf[kki][n], acc[m][n]);
    __syncthreads();
  }

  // ---- epilogue ----
  const int sect = bn >> 4;    // 0=q 1=k 2=v
  const int h = bn & 15;
  if (sect == 2) {
#pragma unroll
    for (int n = 0; n < 4; ++n) {
      const int col = bn * 128 + wc * 64 + n * 16 + colq;
      const float bv = bias[col];
#pragma unroll
      for (int m = 0; m < 4; ++m) {
        const int row0 = bm * 128 + wr * 64 + m * 16 + 4 * g;
#pragma unroll
        for (int r = 0; r < 4; ++r)
          qkvb[(size_t)(row0 + r) * 6144 + col] = (f16)(acc[m][n][r] + bv);
      }
    }
  } else {
    f16* Out = sect ? Kb : Qb;
    const float SQ = 0.088388347648318447f * 1.4426950408889634f;
    const float scale = sect ? 1.0f : SQ;
    const float2* tbl2 = (const float2*)tbl;
#pragma unroll
    for (int n = 0; n < 4; ++n) {
      const int col = bn * 128 + wc * 64 + n * 16 + colq;
      const int d = col & 127;
      const int dd = d >> 1;
      const bool odd = (d & 1) != 0;
      const float bv = bias[col];
#pragma unroll
      for (int m = 0; m < 4; ++m) {
        const int row0 = bm * 128 + wr * 64 + m * 16 + 4 * g;
#pragma unroll
        for (int r = 0; r < 4; ++r) {
          const int row = row0 + r;
          const int t = row & 2047;
          const int b = row >> 11;
          float v = acc[m][n][r] + bv;
          float p = __shfl_xor(v, 1);
          float2 cs = tbl2[t * 64 + dd];
          float o = odd ? (v * cs.x + p * cs.y) : (v * cs.x - p * cs.y);
          Out[((size_t)(b * 16 + h) * 2048 + t) * 128 + d] = (f16)(o * scale);
        }
      }
    }
  }
}

// ---------------- GEMM B: 128x256 tile, depth-2 counted vmcnt (out-proj; R8 measured) ----------------
template <int F32OUT>
__global__ __launch_bounds__(512, 2) void k_gemm128(const f16* __restrict__ A,
                                                    const f16* __restrict__ Bt,
                                                    const float* __restrict__ bias,
                                                    void* __restrict__ Cp,
                                                    int M, int N, int K, int gy) {
  __shared__ f16 lds[2][24576];  // per buf: A[128][64] then B[256][64]
  const int tid = threadIdx.x;
  const int w = tid >> 6, lane = tid & 63;
  const int g = lane >> 4, colq = lane & 15;
  const int wr = w >> 2, wc = w & 3;

  const int nwg = gridDim.x;
  const int q8 = nwg >> 3;
  const int swz = (blockIdx.x & 7) * q8 + (blockIdx.x >> 3);
  const int bm = swz % gy, bn = swz / gy;

  const f16* Ab = A + (size_t)bm * 128 * K;
  const f16* Bb = Bt + (size_t)bn * 256 * K;

  const int srow = lane >> 3;
  const int schunk = (lane & 7) ^ srow;
  const int nt = K >> 6;

  auto STAGE = [&](int kt, f16* buf) {
    const int k0 = kt << 6;
    f16* bA = buf;
    f16* bB = buf + 128 * 64;
#pragma unroll
    for (int j = 0; j < 2; ++j) {
      const int r = w * 16 + j * 8;
      gl_lds16(Ab + (size_t)(r + srow) * K + k0 + schunk * 8, bA + r * 64);
    }
#pragma unroll
    for (int j = 0; j < 4; ++j) {
      const int r = w * 32 + j * 8;
      gl_lds16(Bb + (size_t)(r + srow) * K + k0 + schunk * 8, bB + r * 64);
    }
  };

  STAGE(0, lds[0]);
  STAGE(1, lds[1]);
  asm volatile("s_waitcnt vmcnt(6)" ::: "memory");
  __builtin_amdgcn_s_barrier();

  f4 acc[4][4] = {};
  const int rowA0 = wr * 64 + colq;
  const int rowB0 = wc * 64 + colq;
  const int cq7 = colq & 7;

  for (int t = 0; t < nt; ++t) {
    f16* cur = lds[t & 1];
    h8 af[2][4], bf[2][4];
#pragma unroll
    for (int kki = 0; kki < 2; ++kki) {
#pragma unroll
      for (int m = 0; m < 4; ++m)
        af[kki][m] = *(const h8*)(cur + (rowA0 + m * 16) * 64 + (((kki * 4 + g) ^ cq7) * 8));
#pragma unroll
      for (int n = 0; n < 4; ++n)
        bf[kki][n] = *(const h8*)(cur + 8192 + (rowB0 + n * 16) * 64 + (((kki * 4 + g) ^ cq7) * 8));
    }
    asm volatile("s_waitcnt lgkmcnt(0)" ::: "memory");
    __builtin_amdgcn_s_barrier();
    const bool more = (t + 2 < nt);
    if (more) STAGE(t + 2, cur);
    __builtin_amdgcn_s_setprio(1);
#pragma unroll
    for (int m = 0; m < 4; ++m)
#pragma unroll
      for (int n = 0; n < 4; ++n)
#pragma unroll
        for (int kki = 0; kki < 2; ++kki)
          acc[m][n] = mfma16(af[kki][m], bf[kki][n], acc[m][n]);
    __builtin_amdgcn_s_setprio(0);
    if (more) {
      asm volatile("s_waitcnt vmcnt(6)" ::: "memory");
    } else {
      asm volatile("s_waitcnt vmcnt(0)" ::: "memory");
    }
    __builtin_amdgcn_s_barrier();
  }

#pragma unroll
  for (int n = 0; n < 4; ++n) {
    const int col = bn * 256 + wc * 64 + n * 16 + colq;
    const float bv = bias[col];
#pragma unroll
    for (int m = 0; m < 4; ++m) {
      const int row0 = bm * 128 + wr * 64 + m * 16 + 4 * g;
#pragma unroll
      for (int r = 0; r < 4; ++r) {
        float v = acc[m][n][r] + bv;
        if constexpr (F32OUT) {
          ((float*)Cp)[(size_t)(row0 + r) * N + col] = v;
        } else {
          ((f16*)Cp)[(size_t)(row0 + r) * N + col] = (f16)v;
        }
      }
    }
  }
}

// ---------------- V transpose: qkvb v-section -> Vt[bh][d][t] ----------------
__global__ __launch_bounds__(256) void k_vtrans(const f16* __restrict__ qkv,
                                                f16* __restrict__ Vt) {
  __shared__ f16 ldsT[128 * 40];
  const int bh = blockIdx.y, t0 = blockIdx.x * 32;
  const int b = bh >> 4, h = bh & 15;
  const int tid = threadIdx.x;
#pragma unroll
  for (int cc = 0; cc < 2; ++cc) {
    int task = tid + cc * 256;
    int row = task >> 4;
    int ch = task & 15;
    h8 v = *(const h8*)(qkv + (size_t)(b * 2048 + t0 + row) * 6144 + 4096 + h * 128 + ch * 8);
#pragma unroll
    for (int j = 0; j < 8; ++j) ldsT[(ch * 8 + j) * 40 + row] = v[j];
  }
  __syncthreads();
  int d = tid >> 1, seg = tid & 1;
  h8 v0 = *(const h8*)(ldsT + d * 40 + seg * 16);
  h8 v1 = *(const h8*)(ldsT + d * 40 + seg * 16 + 8);
  f16* dst = Vt + ((size_t)bh * 128 + d) * 2048 + t0 + seg * 16;
  *(h8*)dst = v0;
  *(h8*)(dst + 8) = v1;
}

// ---------------- causal flash attention: 64-row panels, 4 blocks/CU, single-buffer ----------------
DEVI void stage_tiles(const f16* __restrict__ Kg, const f16* __restrict__ Vtg,
                      f16* bufK, f16* bufV, int kv, int w, int lane) {
#pragma unroll
  for (int jj = 0; jj < 4; ++jj) {
    const int j = w * 4 + jj;
    const int rK = j * 4 + (lane >> 4);
    const int cK = (lane & 15) ^ ((rK & 7) << 1);
    gl_lds16(Kg + (size_t)(kv + rK) * 128 + cK * 8, bufK + j * 512);
    const int rV = j * 8 + (lane >> 3);
    const int cV = (lane & 7) ^ (rV & 7);
    gl_lds16(Vtg + (size_t)rV * 2048 + kv + cV * 8, bufV + j * 512);
  }
}

__global__ __launch_bounds__(256) void k_attn(const f16* __restrict__ Q,
                                              const f16* __restrict__ K,
                                              const f16* __restrict__ Vt,
                                              f16* __restrict__ O) {
  __shared__ f16 lds[16384];  // K tile [0,8192), V tile [8192,16384) — single buffer, 32KB
  const int tid = threadIdx.x;
  const int w = tid >> 6, lane = tid & 63;
  const int g = lane >> 4, q = lane & 15;
  const int bid = blockIdx.x;
  const int bh = bid & 31;
  const int k4 = bid >> 8;           // quarter 0..3
  const int r = (bid >> 5) & 7;      // 0..7
  const int p = (k4 == 0) ? (2 * r) : (k4 == 1) ? (2 * r + 1)
              : (k4 == 2) ? (31 - 2 * r) : (30 - 2 * r);  // 64-row panel 0..31

  const f16* Kg = K + (size_t)bh * 2048 * 128;
  const f16* Vtg = Vt + (size_t)bh * 128 * 2048;
  const int qx2 = (q & 7) << 1;
  const int qx = q & 7;

  const int q0w = p * 64 + w * 16;   // wave's 16 q-rows
  const int nit = p + 1;

  h8 qf[4];
#pragma unroll
  for (int d4 = 0; d4 < 4; ++d4)
    qf[d4] = *(const h8*)(Q + ((size_t)bh * 2048 + q0w + q) * 128 + d4 * 32 + g * 8);

  f4 ot[8] = {};
  float mrun = -3.0e38f, lrun = 0.f;

  for (int it = 0; it < nit; ++it) {
    const int kv0 = it * 64;
    stage_tiles(Kg, Vtg, lds, lds + 8192, kv0, w, lane);
    asm volatile("s_waitcnt vmcnt(0)" ::: "memory");
    __builtin_amdgcn_s_barrier();

    f4 st[4] = {{0.f,0.f,0.f,0.f},{0.f,0.f,0.f,0.f},{0.f,0.f,0.f,0.f},{0.f,0.f,0.f,0.f}};
#pragma unroll
    for (int d4 = 0; d4 < 4; ++d4) {
      h8 kf[4];
#pragma unroll
      for (int s = 0; s < 4; ++s)
        kf[s] = *(const h8*)(lds + ((16 * s + q) * 16 + ((4 * d4 + g) ^ qx2)) * 8);
#pragma unroll
      for (int s = 0; s < 4; ++s)
        st[s] = mfma16(kf[s], qf[d4], st[s]);
    }
    if (kv0 + 63 > q0w) {
      const int qcol = q0w + q;
#pragma unroll
      for (int s = 0; s < 4; ++s)
#pragma unroll
        for (int rr = 0; rr < 4; ++rr)
          if (kv0 + s * 16 + 4 * g + rr > qcol) st[s][rr] = -3.0e38f;
    }
    float pm = st[0][0];
#pragma unroll
    for (int s = 0; s < 4; ++s)
#pragma unroll
      for (int rr = 0; rr < 4; ++rr) pm = fmaxf(pm, st[s][rr]);
    pm = fmaxf(pm, __shfl_xor(pm, 16));
    pm = fmaxf(pm, __shfl_xor(pm, 32));
    if (!__all(pm <= mrun + 8.0f)) {
      float mnew = fmaxf(mrun, pm);
      float corr = exp2f(mrun - mnew);
      lrun *= corr;
#pragma unroll
      for (int dt = 0; dt < 8; ++dt) ot[dt] *= corr;
      mrun = mnew;
    }
    float ps = 0.f;
#pragma unroll
    for (int s = 0; s < 4; ++s)
#pragma unroll
      for (int rr = 0; rr < 4; ++rr) {
        st[s][rr] = exp2f(st[s][rr] - mrun);
        ps += st[s][rr];
      }
    ps += __shfl_xor(ps, 16);
    ps += __shfl_xor(ps, 32);
    lrun += ps;

    union { u32 u[4]; h8 h; } pb[2];
    const int s0l = ((g & 1) << 5) | q;
    const bool hi = g >= 2;
#pragma unroll
    for (int hh = 0; hh < 2; ++hh) {
      u32 wA0 = pkh2(st[2 * hh][0], st[2 * hh][1]);
      u32 wB0 = pkh2(st[2 * hh][2], st[2 * hh][3]);
      u32 wA1 = pkh2(st[2 * hh + 1][0], st[2 * hh + 1][1]);
      u32 wB1 = pkh2(st[2 * hh + 1][2], st[2 * hh + 1][3]);
      u32 a0 = (u32)__shfl((int)wA0, s0l),      a1 = (u32)__shfl((int)wA1, s0l);
      u32 b0 = (u32)__shfl((int)wB0, s0l),      b1 = (u32)__shfl((int)wB1, s0l);
      u32 c0 = (u32)__shfl((int)wA0, s0l + 16), c1 = (u32)__shfl((int)wA1, s0l + 16);
      u32 d0 = (u32)__shfl((int)wB0, s0l + 16), d1 = (u32)__shfl((int)wB1, s0l + 16);
      pb[hh].u[0] = hi ? a1 : a0;
      pb[hh].u[1] = hi ? b1 : b0;
      pb[hh].u[2] = hi ? c1 : c0;
      pb[hh].u[3] = hi ? d1 : d0;
    }
#pragma unroll
    for (int hh = 0; hh < 2; ++hh)
#pragma unroll
      for (int dt = 0; dt < 8; ++dt) {
        h8 vf = *(const h8*)(lds + 8192 + ((dt * 16 + q) * 8 + ((4 * hh + g) ^ qx)) * 8);
        ot[dt] = mfma16(vf, pb[hh].h, ot[dt]);
      }

    __builtin_amdgcn_s_barrier();  // all waves done reading before next stage overwrites
  }

  float linv = 1.0f / lrun;
  f16* Ob = O + ((size_t)(bh >> 4) * 2048 + q0w + q) * 2048 + (bh & 15) * 128 + 4 * g;
#pragma unroll
  for (int dt = 0; dt < 8; ++dt) {
    union { f16 hh4[4]; u64 u; } o;
#pragma unroll
    for (int rr = 0; rr < 4; ++rr) o.hh4[rr] = (f16)(ot[dt][rr] * linv);
    *(u64*)(Ob + dt * 16) = o.u;
  }
}

// ---------------- launch ----------------
extern "C" void kernel_launch(void* const* d_in, const int* in_sizes, int n_in,
                              void* d_out, int out_size, void* d_ws, size_t ws_size,
                              hipStream_t stream) {
  (void)in_sizes; (void)n_in; (void)out_size; (void)ws_size;
  const float* x    = (const float*)d_in[0];
  const float* Wqkv = (const float*)d_in[1];
  const float* bqkv = (const float*)d_in[2];
  const float* Wo   = (const float*)d_in[3];
  const float* bo   = (const float*)d_in[4];

  char* ws = (char*)d_ws;
  f16* xb    = (f16*)ws; ws += (size_t)4096 * 2048 * 2;
  f16* wqkvb = (f16*)ws; ws += (size_t)6144 * 2048 * 2;
  f16* wob   = (f16*)ws; ws += (size_t)2048 * 2048 * 2;
  f16* qkvb  = (f16*)ws; ws += (size_t)4096 * 6144 * 2;
  f16* Qb    = (f16*)ws; ws += (size_t)32 * 2048 * 128 * 2;
  f16* Kb    = (f16*)ws; ws += (size_t)32 * 2048 * 128 * 2;
  f16* Vtb   = (f16*)ws; ws += (size_t)32 * 128 * 2048 * 2;
  f16* attb  = (f16*)ws; ws += (size_t)4096 * 2048 * 2;
  float* tbl = (float*)ws; ws += (size_t)2048 * 64 * 2 * 4;

  // converts + rope table in one launch
  k_prep<<<25088, 256, 0, stream>>>(x, Wqkv, Wo, xb, wqkvb, wob, tbl);

  // QKV with fused RoPE epilogue: 1536 blocks
  k_gemm_qkv<<<1536, 256, 0, stream>>>(xb, wqkvb, bqkv, tbl, Qb, Kb, qkvb, 2048);

  // V transpose (reads qkvb v-section only)
  k_vtrans<<<dim3(64, 32), 256, 0, stream>>>(qkvb, Vtb);

  // attention: 1024 blocks = 4/CU, 64-row panels, single-buffer 32KB, balanced quarters
  k_attn<<<1024, 256, 0, stream>>>(Qb, Kb, Vtb, attb);

  // out-proj: 128x256 tiles, 256 blocks (1 exact round)
  k_gemm128<1><<<256, 512, 0, stream>>>(attb, wob, bo, d_out, 4096, 2048, 2048, 32);
}

// Round 27
// 305.625 us; speedup vs baseline: 1.0067x; 1.0067x over previous
//
#include <hip/hip_runtime.h>

using f16 = _Float16;
typedef _Float16 h8 __attribute__((ext_vector_type(8)));
typedef _Float16 h4 __attribute__((ext_vector_type(4)));
typedef float f4 __attribute__((ext_vector_type(4)));
typedef unsigned int u32;
typedef unsigned long long u64;

#define DEVI static __device__ __forceinline__

DEVI f4 mfma16(h8 a, h8 b, f4 c) {
  return __builtin_amdgcn_mfma_f32_16x16x32_f16(a, b, c, 0, 0, 0);
}

// async global->LDS, 16B per lane. lds base must be wave-uniform; HW scatters lane i at base + i*16.
DEVI void gl_lds16(const f16* g, f16* l) {
  __builtin_amdgcn_global_load_lds(
      (const __attribute__((address_space(1))) u32*)g,
      (__attribute__((address_space(3))) u32*)l, 16, 0, 0);
}

DEVI u32 pkh2(float a, float b) {
  union { f16 h[2]; u32 u; } x;
  x.h[0] = (f16)a; x.h[1] = (f16)b;
  return x.u;
}

typedef float fv4 __attribute__((ext_vector_type(4)));

// ---------------- fused prep: fp32->fp16 converts (x, Wqkv, Wo) + RoPE table ----------------
__global__ __launch_bounds__(256) void k_prep(const float* __restrict__ x,
                                              const float* __restrict__ wqkv,
                                              const float* __restrict__ wo,
                                              f16* __restrict__ xb,
                                              f16* __restrict__ wqkvb,
                                              f16* __restrict__ wob,
                                              float* __restrict__ tbl) {
  int i = blockIdx.x * 256 + threadIdx.x;
  if (i < 6291456) {
    const float* src; f16* dst; int off;
    if (i < 2097152)      { src = x;    dst = xb;    off = i; }
    else if (i < 5242880) { src = wqkv; dst = wqkvb; off = i - 2097152; }
    else                  { src = wo;   dst = wob;   off = i - 5242880; }
    fv4 v = ((const fv4*)src)[off];
    h4 o;
    o[0] = (f16)v[0]; o[1] = (f16)v[1]; o[2] = (f16)v[2]; o[3] = (f16)v[3];
    ((h4*)dst)[off] = o;
  } else {
    int i2 = i - 6291456;  // < 131072
    int t = i2 >> 6, d = i2 & 63;
    float invf = exp2f(-(float)d * (13.287712379549449f / 64.f));
    float a = (float)t * invf;
    tbl[2 * i2]     = cosf(a);
    tbl[2 * i2 + 1] = sinf(a);
  }
}

// ---------------- QKV GEMM: m97 structure + fused RoPE epilogue (best-total, 8x verified) ----------------
__global__ __launch_bounds__(256) void k_gemm_qkv(const f16* __restrict__ A,
                                                  const f16* __restrict__ Bt,
                                                  const float* __restrict__ bias,
                                                  const float* __restrict__ tbl,
                                                  f16* __restrict__ Qb,
                                                  f16* __restrict__ Kb,
                                                  f16* __restrict__ qkvb,
                                                  int K) {
  __shared__ f16 sA[128 * 64];
  __shared__ f16 sB[128 * 64];
  const int tid = threadIdx.x;
  const int w = tid >> 6, lane = tid & 63;
  const int g = lane >> 4, colq = lane & 15;
  const int wr = w >> 1, wc = w & 1;

  const int nwg = gridDim.x;
  const int q8 = nwg >> 3;
  const int swz = (blockIdx.x & 7) * q8 + (blockIdx.x >> 3);
  const int bm = swz & 31, bn = swz >> 5;  // gy = 32

  const f16* Ab = A + (size_t)bm * 128 * K;
  const f16* Bb = Bt + (size_t)bn * 128 * K;
  const int nt = K >> 6;

  const int srow = lane >> 3;
  const int schunk = (lane & 7) ^ srow;
  const int cq7 = colq & 7;

  f4 acc[4][4] = {};
  const int rowA0 = wr * 64 + colq;
  const int rowB0 = wc * 64 + colq;

  for (int t = 0; t < nt; ++t) {
    const int k0 = t << 6;
#pragma unroll
    for (int j = 0; j < 4; ++j) {
      const int r = (w * 4 + j) * 8;
      gl_lds16(Ab + (size_t)(r + srow) * K + k0 + schunk * 8, sA + r * 64);
      gl_lds16(Bb + (size_t)(r + srow) * K + k0 + schunk * 8, sB + r * 64);
    }
    __syncthreads();
    h8 af[2][4], bf[2][4];
#pragma unroll
    for (int kki = 0; kki < 2; ++kki) {
#pragma unroll
      for (int m = 0; m < 4; ++m)
        af[kki][m] = *(const h8*)(sA + (rowA0 + m * 16) * 64 + (((kki * 4 + g) ^ cq7) * 8));
#pragma unroll
      for (int n = 0; n < 4; ++n)
        bf[kki][n] = *(const h8*)(sB + (rowB0 + n * 16) * 64 + (((kki * 4 + g) ^ cq7) * 8));
    }
#pragma unroll
    for (int m = 0; m < 4; ++m)
#pragma unroll
      for (int n = 0; n < 4; ++n)
#pragma unroll
        for (int kki = 0; kki < 2; ++kki)
          acc[m][n] = mfma16(af[kki][m], bf[kki][n], acc[m][n]);
    __syncthreads();
  }

  // ---- epilogue ----
  const int sect = bn >> 4;    // 0=q 1=k 2=v
  const int h = bn & 15;
  if (sect == 2) {
#pragma unroll
    for (int n = 0; n < 4; ++n) {
      const int col = bn * 128 + wc * 64 + n * 16 + colq;
      const float bv = bias[col];
#pragma unroll
      for (int m = 0; m < 4; ++m) {
        const int row0 = bm * 128 + wr * 64 + m * 16 + 4 * g;
#pragma unroll
        for (int r = 0; r < 4; ++r)
          qkvb[(size_t)(row0 + r) * 6144 + col] = (f16)(acc[m][n][r] + bv);
      }
    }
  } else {
    f16* Out = sect ? Kb : Qb;
    const float SQ = 0.088388347648318447f * 1.4426950408889634f;
    const float scale = sect ? 1.0f : SQ;
    const float2* tbl2 = (const float2*)tbl;
#pragma unroll
    for (int n = 0; n < 4; ++n) {
      const int col = bn * 128 + wc * 64 + n * 16 + colq;
      const int d = col & 127;
      const int dd = d >> 1;
      const bool odd = (d & 1) != 0;
      const float bv = bias[col];
#pragma unroll
      for (int m = 0; m < 4; ++m) {
        const int row0 = bm * 128 + wr * 64 + m * 16 + 4 * g;
#pragma unroll
        for (int r = 0; r < 4; ++r) {
          const int row = row0 + r;
          const int t = row & 2047;
          const int b = row >> 11;
          float v = acc[m][n][r] + bv;
          float p = __shfl_xor(v, 1);
          float2 cs = tbl2[t * 64 + dd];
          float o = odd ? (v * cs.x + p * cs.y) : (v * cs.x - p * cs.y);
          Out[((size_t)(b * 16 + h) * 2048 + t) * 128 + d] = (f16)(o * scale);
        }
      }
    }
  }
}

// ---------------- GEMM B: 128x256 tile, depth-2 counted vmcnt (out-proj; R8 measured) ----------------
template <int F32OUT>
__global__ __launch_bounds__(512, 2) void k_gemm128(const f16* __restrict__ A,
                                                    const f16* __restrict__ Bt,
                                                    const float* __restrict__ bias,
                                                    void* __restrict__ Cp,
                                                    int M, int N, int K, int gy) {
  __shared__ f16 lds[2][24576];  // per buf: A[128][64] then B[256][64]
  const int tid = threadIdx.x;
  const int w = tid >> 6, lane = tid & 63;
  const int g = lane >> 4, colq = lane & 15;
  const int wr = w >> 2, wc = w & 3;

  const int nwg = gridDim.x;
  const int q8 = nwg >> 3;
  const int swz = (blockIdx.x & 7) * q8 + (blockIdx.x >> 3);
  const int bm = swz % gy, bn = swz / gy;

  const f16* Ab = A + (size_t)bm * 128 * K;
  const f16* Bb = Bt + (size_t)bn * 256 * K;

  const int srow = lane >> 3;
  const int schunk = (lane & 7) ^ srow;
  const int nt = K >> 6;

  auto STAGE = [&](int kt, f16* buf) {
    const int k0 = kt << 6;
    f16* bA = buf;
    f16* bB = buf + 128 * 64;
#pragma unroll
    for (int j = 0; j < 2; ++j) {
      const int r = w * 16 + j * 8;
      gl_lds16(Ab + (size_t)(r + srow) * K + k0 + schunk * 8, bA + r * 64);
    }
#pragma unroll
    for (int j = 0; j < 4; ++j) {
      const int r = w * 32 + j * 8;
      gl_lds16(Bb + (size_t)(r + srow) * K + k0 + schunk * 8, bB + r * 64);
    }
  };

  STAGE(0, lds[0]);
  STAGE(1, lds[1]);
  asm volatile("s_waitcnt vmcnt(6)" ::: "memory");
  __builtin_amdgcn_s_barrier();

  f4 acc[4][4] = {};
  const int rowA0 = wr * 64 + colq;
  const int rowB0 = wc * 64 + colq;
  const int cq7 = colq & 7;

  for (int t = 0; t < nt; ++t) {
    f16* cur = lds[t & 1];
    h8 af[2][4], bf[2][4];
#pragma unroll
    for (int kki = 0; kki < 2; ++kki) {
#pragma unroll
      for (int m = 0; m < 4; ++m)
        af[kki][m] = *(const h8*)(cur + (rowA0 + m * 16) * 64 + (((kki * 4 + g) ^ cq7) * 8));
#pragma unroll
      for (int n = 0; n < 4; ++n)
        bf[kki][n] = *(const h8*)(cur + 8192 + (rowB0 + n * 16) * 64 + (((kki * 4 + g) ^ cq7) * 8));
    }
    asm volatile("s_waitcnt lgkmcnt(0)" ::: "memory");
    __builtin_amdgcn_s_barrier();
    const bool more = (t + 2 < nt);
    if (more) STAGE(t + 2, cur);
    __builtin_amdgcn_s_setprio(1);
#pragma unroll
    for (int m = 0; m < 4; ++m)
#pragma unroll
      for (int n = 0; n < 4; ++n)
#pragma unroll
        for (int kki = 0; kki < 2; ++kki)
          acc[m][n] = mfma16(af[kki][m], bf[kki][n], acc[m][n]);
    __builtin_amdgcn_s_setprio(0);
    if (more) {
      asm volatile("s_waitcnt vmcnt(6)" ::: "memory");
    } else {
      asm volatile("s_waitcnt vmcnt(0)" ::: "memory");
    }
    __builtin_amdgcn_s_barrier();
  }

#pragma unroll
  for (int n = 0; n < 4; ++n) {
    const int col = bn * 256 + wc * 64 + n * 16 + colq;
    const float bv = bias[col];
#pragma unroll
    for (int m = 0; m < 4; ++m) {
      const int row0 = bm * 128 + wr * 64 + m * 16 + 4 * g;
#pragma unroll
      for (int r = 0; r < 4; ++r) {
        float v = acc[m][n][r] + bv;
        if constexpr (F32OUT) {
          ((float*)Cp)[(size_t)(row0 + r) * N + col] = v;
        } else {
          ((f16*)Cp)[(size_t)(row0 + r) * N + col] = (f16)v;
        }
      }
    }
  }
}

// ---------------- V transpose: qkvb v-section -> Vt[bh][d][t] ----------------
__global__ __launch_bounds__(256) void k_vtrans(const f16* __restrict__ qkv,
                                                f16* __restrict__ Vt) {
  __shared__ f16 ldsT[128 * 40];
  const int bh = blockIdx.y, t0 = blockIdx.x * 32;
  const int b = bh >> 4, h = bh & 15;
  const int tid = threadIdx.x;
#pragma unroll
  for (int cc = 0; cc < 2; ++cc) {
    int task = tid + cc * 256;
    int row = task >> 4;
    int ch = task & 15;
    h8 v = *(const h8*)(qkv + (size_t)(b * 2048 + t0 + row) * 6144 + 4096 + h * 128 + ch * 8);
#pragma unroll
    for (int j = 0; j < 8; ++j) ldsT[(ch * 8 + j) * 40 + row] = v[j];
  }
  __syncthreads();
  int d = tid >> 1, seg = tid & 1;
  h8 v0 = *(const h8*)(ldsT + d * 40 + seg * 16);
  h8 v1 = *(const h8*)(ldsT + d * 40 + seg * 16 + 8);
  f16* dst = Vt + ((size_t)bh * 128 + d) * 2048 + t0 + seg * 16;
  *(h8*)dst = v0;
  *(h8*)(dst + 8) = v1;
}

// ---------------- causal flash attention: 64-row panels, 4 blocks/CU, single-buffer ----------------
DEVI void stage_tiles(const f16* __restrict__ Kg, const f16* __restrict__ Vtg,
                      f16* bufK, f16* bufV, int kv, int w, int lane) {
#pragma unroll
  for (int jj = 0; jj < 4; ++jj) {
    const int j = w * 4 + jj;
    const int rK = j * 4 + (lane >> 4);
    const int cK = (lane & 15) ^ ((rK & 7) << 1);
    gl_lds16(Kg + (size_t)(kv + rK) * 128 + cK * 8, bufK + j * 512);
    const int rV = j * 8 + (lane >> 3);
    const int cV = (lane & 7) ^ (rV & 7);
    gl_lds16(Vtg + (size_t)rV * 2048 + kv + cV * 8, bufV + j * 512);
  }
}

__global__ __launch_bounds__(256) void k_attn(const f16* __restrict__ Q,
                                              const f16* __restrict__ K,
                                              const f16* __restrict__ Vt,
                                              f16* __restrict__ O) {
  __shared__ f16 lds[16384];  // K tile [0,8192), V tile [8192,16384) — single buffer, 32KB
  const int tid = threadIdx.x;
  const int w = tid >> 6, lane = tid & 63;
  const int g = lane >> 4, q = lane & 15;
  const int bid = blockIdx.x;
  const int bh = bid & 31;
  const int k4 = bid >> 8;           // quarter 0..3
  const int r = (bid >> 5) & 7;      // 0..7
  const int p = (k4 == 0) ? (2 * r) : (k4 == 1) ? (2 * r + 1)
              : (k4 == 2) ? (31 - 2 * r) : (30 - 2 * r);  // 64-row panel 0..31

  const f16* Kg = K + (size_t)bh * 2048 * 128;
  const f16* Vtg = Vt + (size_t)bh * 128 * 2048;
  const int qx2 = (q & 7) << 1;
  const int qx = q & 7;

  const int q0w = p * 64 + w * 16;   // wave's 16 q-rows
  const int nit = p + 1;

  h8 qf[4];
#pragma unroll
  for (int d4 = 0; d4 < 4; ++d4)
    qf[d4] = *(const h8*)(Q + ((size_t)bh * 2048 + q0w + q) * 128 + d4 * 32 + g * 8);

  f4 ot[8] = {};
  float mrun = -3.0e38f, lrun = 0.f;

  for (int it = 0; it < nit; ++it) {
    const int kv0 = it * 64;
    stage_tiles(Kg, Vtg, lds, lds + 8192, kv0, w, lane);
    asm volatile("s_waitcnt vmcnt(0)" ::: "memory");
    __builtin_amdgcn_s_barrier();

    f4 st[4] = {{0.f,0.f,0.f,0.f},{0.f,0.f,0.f,0.f},{0.f,0.f,0.f,0.f},{0.f,0.f,0.f,0.f}};
#pragma unroll
    for (int d4 = 0; d4 < 4; ++d4) {
      h8 kf[4];
#pragma unroll
      for (int s = 0; s < 4; ++s)
        kf[s] = *(const h8*)(lds + ((16 * s + q) * 16 + ((4 * d4 + g) ^ qx2)) * 8);
#pragma unroll
      for (int s = 0; s < 4; ++s)
        st[s] = mfma16(kf[s], qf[d4], st[s]);
    }
    if (kv0 + 63 > q0w) {
      const int qcol = q0w + q;
#pragma unroll
      for (int s = 0; s < 4; ++s)
#pragma unroll
        for (int rr = 0; rr < 4; ++rr)
          if (kv0 + s * 16 + 4 * g + rr > qcol) st[s][rr] = -3.0e38f;
    }
    float pm = st[0][0];
#pragma unroll
    for (int s = 0; s < 4; ++s)
#pragma unroll
      for (int rr = 0; rr < 4; ++rr) pm = fmaxf(pm, st[s][rr]);
    pm = fmaxf(pm, __shfl_xor(pm, 16));
    pm = fmaxf(pm, __shfl_xor(pm, 32));
    if (!__all(pm <= mrun + 8.0f)) {
      float mnew = fmaxf(mrun, pm);
      float corr = exp2f(mrun - mnew);
      lrun *= corr;
#pragma unroll
      for (int dt = 0; dt < 8; ++dt) ot[dt] *= corr;
      mrun = mnew;
    }
    float ps = 0.f;
#pragma unroll
    for (int s = 0; s < 4; ++s)
#pragma unroll
      for (int rr = 0; rr < 4; ++rr) {
        st[s][rr] = exp2f(st[s][rr] - mrun);
        ps += st[s][rr];
      }
    ps += __shfl_xor(ps, 16);
    ps += __shfl_xor(ps, 32);
    lrun += ps;

    union { u32 u[4]; h8 h; } pb[2];
    const int s0l = ((g & 1) << 5) | q;
    const bool hi = g >= 2;
#pragma unroll
    for (int hh = 0; hh < 2; ++hh) {
      u32 wA0 = pkh2(st[2 * hh][0], st[2 * hh][1]);
      u32 wB0 = pkh2(st[2 * hh][2], st[2 * hh][3]);
      u32 wA1 = pkh2(st[2 * hh + 1][0], st[2 * hh + 1][1]);
      u32 wB1 = pkh2(st[2 * hh + 1][2], st[2 * hh + 1][3]);
      u32 a0 = (u32)__shfl((int)wA0, s0l),      a1 = (u32)__shfl((int)wA1, s0l);
      u32 b0 = (u32)__shfl((int)wB0, s0l),      b1 = (u32)__shfl((int)wB1, s0l);
      u32 c0 = (u32)__shfl((int)wA0, s0l + 16), c1 = (u32)__shfl((int)wA1, s0l + 16);
      u32 d0 = (u32)__shfl((int)wB0, s0l + 16), d1 = (u32)__shfl((int)wB1, s0l + 16);
      pb[hh].u[0] = hi ? a1 : a0;
      pb[hh].u[1] = hi ? b1 : b0;
      pb[hh].u[2] = hi ? c1 : c0;
      pb[hh].u[3] = hi ? d1 : d0;
    }
#pragma unroll
    for (int hh = 0; hh < 2; ++hh)
#pragma unroll
      for (int dt = 0; dt < 8; ++dt) {
        h8 vf = *(const h8*)(lds + 8192 + ((dt * 16 + q) * 8 + ((4 * hh + g) ^ qx)) * 8);
        ot[dt] = mfma16(vf, pb[hh].h, ot[dt]);
      }

    __builtin_amdgcn_s_barrier();  // all waves done reading before next stage overwrites
  }

  float linv = 1.0f / lrun;
  f16* Ob = O + ((size_t)(bh >> 4) * 2048 + q0w + q) * 2048 + (bh & 15) * 128 + 4 * g;
#pragma unroll
  for (int dt = 0; dt < 8; ++dt) {
    union { f16 hh4[4]; u64 u; } o;
#pragma unroll
    for (int rr = 0; rr < 4; ++rr) o.hh4[rr] = (f16)(ot[dt][rr] * linv);
    *(u64*)(Ob + dt * 16) = o.u;
  }
}

// ---------------- launch ----------------
extern "C" void kernel_launch(void* const* d_in, const int* in_sizes, int n_in,
                              void* d_out, int out_size, void* d_ws, size_t ws_size,
                              hipStream_t stream) {
  (void)in_sizes; (void)n_in; (void)out_size; (void)ws_size;
  const float* x    = (const float*)d_in[0];
  const float* Wqkv = (const float*)d_in[1];
  const float* bqkv = (const float*)d_in[2];
  const float* Wo   = (const float*)d_in[3];
  const float* bo   = (const float*)d_in[4];

  char* ws = (char*)d_ws;
  f16* xb    = (f16*)ws; ws += (size_t)4096 * 2048 * 2;
  f16* wqkvb = (f16*)ws; ws += (size_t)6144 * 2048 * 2;
  f16* wob   = (f16*)ws; ws += (size_t)2048 * 2048 * 2;
  f16* qkvb  = (f16*)ws; ws += (size_t)4096 * 6144 * 2;
  f16* Qb    = (f16*)ws; ws += (size_t)32 * 2048 * 128 * 2;
  f16* Kb    = (f16*)ws; ws += (size_t)32 * 2048 * 128 * 2;
  f16* Vtb   = (f16*)ws; ws += (size_t)32 * 128 * 2048 * 2;
  f16* attb  = (f16*)ws; ws += (size_t)4096 * 2048 * 2;
  float* tbl = (float*)ws; ws += (size_t)2048 * 64 * 2 * 4;

  // converts + rope table in one launch
  k_prep<<<25088, 256, 0, stream>>>(x, Wqkv, Wo, xb, wqkvb, wob, tbl);

  // QKV with fused RoPE epilogue: 1536 blocks
  k_gemm_qkv<<<1536, 256, 0, stream>>>(xb, wqkvb, bqkv, tbl, Qb, Kb, qkvb, 2048);

  // V transpose (reads qkvb v-section only)
  k_vtrans<<<dim3(64, 32), 256, 0, stream>>>(qkvb, Vtb);

  // attention: 1024 blocks = 4/CU, 64-row panels, single-buffer 32KB, balanced quarters
  k_attn<<<1024, 256, 0, stream>>>(Qb, Kb, Vtb, attb);

  // out-proj: 128x256 tiles, 256 blocks (1 exact round)
  k_gemm128<1><<<256, 512, 0, stream>>>(attb, wob, bo, d_out, 4096, 2048, 2048, 32);
}